// Round 15
// baseline (1057.786 us; speedup 1.0000x reference)
//
#include <hip/hip_runtime.h>

typedef __attribute__((ext_vector_type(8))) short short8;
typedef __attribute__((ext_vector_type(4))) float f32x4;

#define BATCH   131072
#define IND     300
#define MIDD    450
#define HS      488   // H LDS row stride (elems); 976B: bank step 20 -> 2-way alias (free)
#define WXS     320   // W global row stride, K300-class: 640B = 64B-aligned rows
#define WHS     480   // W global row stride, K450-class: 960B = 64B-aligned rows
#define BM      64    // 131072/64 = 2048 blocks, no tail
#define NTHR    512
#define NBLK    (BATCH / BM)
#define MM      (BM / 16)   // 4 m-tiles

constexpr int SZ1 = 464 * WXS;    // [464][320] padded N450,K320 weights (row-major, bf16)
constexpr int SZ2 = 304 * WHS;    // [304][480] padded N300,K480 weights
constexpr int O_NOT1 = 0;
constexpr int O_NOT2 = SZ1;
constexpr int O_AND1 = SZ1 + SZ2;
constexpr int O_AND2 = 2 * SZ1 + SZ2;
constexpr int O_OR1  = 2 * SZ1 + 2 * SZ2;
constexpr int O_OR2  = 3 * SZ1 + 2 * SZ2;
constexpr int WS_ELEMS = 3 * SZ1 + 3 * SZ2;

constexpr int LDS_BYTES = BM * HS * 2;    // 62464 -> 2 blocks/CU (125KB of 160KB)

__device__ __forceinline__ unsigned short f2b(float f) {
  unsigned u = __builtin_bit_cast(unsigned, f);
  u = (u + 0x7FFFu + ((u >> 16) & 1u)) >> 16;   // RNE
  return (unsigned short)u;
}
__device__ __forceinline__ float b2f(unsigned short h) {
  unsigned u = ((unsigned)h) << 16;
  return __builtin_bit_cast(float, u);
}
__device__ __forceinline__ f32x4 mfma16(short8 a, short8 b, f32x4 c) {
  asm("v_mfma_f32_16x16x32_bf16 %0, %1, %2, %0" : "+v"(c) : "v"(a), "v"(b));
  return c;
}

// ---- weight prep: f32 -> bf16, zero-padded, 64B-aligned rows; AND/OR W1 folded ----
__global__ void prep_weights(const float* __restrict__ nw1, const float* __restrict__ nw2,
                             const float* __restrict__ aw1, const float* __restrict__ aw2,
                             const float* __restrict__ ow1, const float* __restrict__ ow2,
                             unsigned short* __restrict__ ws)
{
  int idx = blockIdx.x * 256 + threadIdx.x;
  if (idx < 3 * SZ1) {
    int r = idx / SZ1, off = idx % SZ1;
    int n = off / WXS, k = off % WXS;
    float v = 0.f;
    if (n < MIDD && k < IND) {
      if (r == 0) v = nw1[n * IND + k];
      else {
        const float* s = (r == 1) ? aw1 : ow1;
        v = s[n * 2 * IND + k] + s[n * 2 * IND + IND + k];   // fold concat([x,x])
      }
    }
    int base = (r == 0) ? O_NOT1 : (r == 1) ? O_AND1 : O_OR1;
    ws[base + off] = f2b(v);
  } else if (idx < WS_ELEMS) {
    int i2 = idx - 3 * SZ1;
    int r = i2 / SZ2, off = i2 % SZ2;
    int n = off / WHS, k = off % WHS;
    float v = 0.f;
    if (n < IND && k < MIDD) {
      const float* s = (r == 0) ? nw2 : (r == 1) ? aw2 : ow2;
      v = s[n * MIDD + k];
    }
    int base = (r == 0) ? O_NOT2 : (r == 1) ? O_AND2 : O_OR2;
    ws[base + off] = f2b(v);
  }
}

// ---- one GEMM stage: OUT[64][N] = leaky(IN @ W^T + b); MSE variant fuses vs f32 x ----
// AFROMX: A packed on the fly from block-local f32 x rows (L2/L3-resident; 16B-aligned
// since 300 f32 = 1200B = 75*16). Else A from LDS H. B from L2, 3-buf depth-2 pipeline.
// Frags (16x16x32 bf16): A lane m=l&15,k=8*(l>>4)+i ; B lane n=l&15,k same
// D lane: n=l&15, m=(l>>4)*4+r  (validated rounds 1-14)
template <int KB, int NT, int N, bool AFROMX, bool MSE>
__device__ __forceinline__ void stage(const unsigned short* __restrict__ Hlds,
                                      const float* __restrict__ xg,   // x + row0*300
                                      const unsigned short* __restrict__ Wg, int wg_stride,
                                      const float* __restrict__ bias,
                                      unsigned short* __restrict__ Hout,
                                      float& sq, int tid, int wn, int l16, int lhi)
{
  constexpr int NJ = (NT + 7) / 8;
  f32x4 acc[MM][NJ];
#pragma unroll
  for (int m = 0; m < MM; m++)
#pragma unroll
    for (int j = 0; j < NJ; j++) acc[m][j] = f32x4{0.f, 0.f, 0.f, 0.f};

  const unsigned short* ah[MM];
  const float* ax[MM];
#pragma unroll
  for (int m = 0; m < MM; m++) {
    ah[m] = Hlds + (m * 16 + l16) * HS + lhi * 8;
    ax[m] = xg + (m * 16 + l16) * IND + lhi * 8;
  }
  const unsigned short* bp[NJ];
#pragma unroll
  for (int j = 0; j < NJ; j++) {
    int nt = wn + 8 * j;
    int row = (nt < NT ? nt : 0) * 16 + l16;      // clamp invalid tiles to row 0
    bp[j] = Wg + row * wg_stride + lhi * 8;
  }

  short8 a0[MM], a1[MM], b0[NJ], b1[NJ], b2[NJ];

#define LA_(buf, kk)                                                          \
  { _Pragma("unroll") for (int m = 0; m < MM; m++) {                          \
      if (AFROMX) {                                                           \
        if ((kk) == KB - 1) {  /* K=300 tail: elements >=300 are zero */      \
          _Pragma("unroll") for (int i = 0; i < 8; i++) {                     \
            int k = (kk) * 32 + lhi * 8 + i;                                  \
            float v = (k < IND) ? ax[m][(kk) * 32 + i] : 0.f;                 \
            buf[m][i] = (short)f2b(v);                                        \
          }                                                                   \
        } else {                                                              \
          f32x4 f0 = *(const f32x4*)(ax[m] + (kk) * 32);                      \
          f32x4 f1 = *(const f32x4*)(ax[m] + (kk) * 32 + 4);                  \
          _Pragma("unroll") for (int i = 0; i < 4; i++) {                     \
            buf[m][i]     = (short)f2b(f0[i]);                                \
            buf[m][i + 4] = (short)f2b(f1[i]);                                \
          }                                                                   \
        }                                                                     \
      } else {                                                                \
        buf[m] = *(const short8*)(ah[m] + (kk) * 32);                         \
      }                                                                       \
    } }
#define LB_(buf, kk)                                                          \
  { _Pragma("unroll") for (int j = 0; j < NJ; j++)                            \
      if (wn + 8 * j < NT) buf[j] = *(const short8*)(bp[j] + (kk) * 32); }

  LB_(b0, 0);
  LB_(b1, 1);
  LA_(a0, 0);

#pragma unroll
  for (int kb = 0; kb < KB; kb++) {
    short8* ac = (kb & 1) ? a1 : a0;
    short8* an = (kb & 1) ? a0 : a1;
    short8* bc = (kb % 3 == 0) ? b0 : (kb % 3 == 1) ? b1 : b2;
    short8* bn = ((kb + 2) % 3 == 0) ? b0 : ((kb + 2) % 3 == 1) ? b1 : b2;
    if (kb + 2 < KB) LB_(bn, kb + 2);     // depth-2 global prefetch (counted vmcnt)
    if (kb + 1 < KB) LA_(an, kb + 1);     // depth-1 A prefetch (LDS or x-pack)
    __builtin_amdgcn_s_setprio(1);
#pragma unroll
    for (int j = 0; j < NJ; j++) {
      if (wn + 8 * j < NT) {
#pragma unroll
        for (int m = 0; m < MM; m++) acc[m][j] = mfma16(ac[m], bc[j], acc[m][j]);
      }
    }
    __builtin_amdgcn_s_setprio(0);
  }
#undef LA_
#undef LB_

  if (!MSE) __syncthreads();   // in-place H overwrite: all waves done reading H

#pragma unroll
  for (int j = 0; j < NJ; j++) {
    int nt = wn + 8 * j;
    if (nt >= NT) continue;
    int col = nt * 16 + l16;
    bool valid = col < N;
    float bv = valid ? bias[col] : 0.f;
#pragma unroll
    for (int m = 0; m < MM; m++) {
#pragma unroll
      for (int r = 0; r < 4; r++) {
        int row = m * 16 + lhi * 4 + r;
        float v = acc[m][j][r] + bv;
        v = v > 0.f ? v : 0.1f * v;
        if (MSE) {
          if (valid) { float d = xg[row * IND + col] - v; sq += d * d; }
        } else {
          if (valid) Hout[row * HS + col] = f2b(v);
        }
      }
    }
  }
  if (!MSE && N == IND) {
    // zero pad cols [300,320) so the next K=320 read sees zeros
    for (int i = tid; i < BM * 20; i += NTHR) {
      int r = i / 20, c = i - r * 20;
      Hout[r * HS + IND + c] = 0;
    }
  }
}

__global__ __launch_bounds__(NTHR)
void fused(const float* __restrict__ x, const unsigned short* __restrict__ ws,
           const float* __restrict__ nb1, const float* __restrict__ nb2,
           const float* __restrict__ ab1, const float* __restrict__ ab2,
           const float* __restrict__ ob1, const float* __restrict__ ob2,
           float* __restrict__ out)
{
  extern __shared__ __align__(16) char smem[];
  unsigned short* H = (unsigned short*)smem;       // [64][HS] only -> 62.5KB, 2 blocks/CU
  __shared__ float wsum[8];
  int tid = threadIdx.x, wid = tid >> 6, lane = tid & 63;
  int l16 = lane & 15, lhi = lane >> 4;

  // zero H (K-pad columns must be 0; cols >=450 stay 0 forever)
  for (int i = tid; i < LDS_BYTES / 4; i += NTHR) ((unsigned*)smem)[i] = 0u;
  __syncthreads();

  const float* xg = x + (size_t)blockIdx.x * BM * IND;
  float sq = 0.f;

  // NOT(NOT(x)): s1 H=leaky(x@W1'+b1); s2 H=leaky(H@W2'+b2) in-place;
  //              s3 H=leaky(H@W1'+b1) in-place; s4 MSE(x, leaky(H@W2'+b2))
  stage<10, 29, MIDD, true,  false>(H, xg, ws + O_NOT1, WXS, nb1, H, sq, tid, wid, l16, lhi);
  __syncthreads();
  stage<15, 19, IND,  false, false>(H, xg, ws + O_NOT2, WHS, nb2, H, sq, tid, wid, l16, lhi);
  __syncthreads();
  stage<10, 29, MIDD, false, false>(H, xg, ws + O_NOT1, WXS, nb1, H, sq, tid, wid, l16, lhi);
  __syncthreads();
  stage<15, 19, IND,  false, true >(H, xg, ws + O_NOT2, WHS, nb2, H, sq, tid, wid, l16, lhi);
  __syncthreads();
  // AND (folded W1)
  stage<10, 29, MIDD, true,  false>(H, xg, ws + O_AND1, WXS, ab1, H, sq, tid, wid, l16, lhi);
  __syncthreads();
  stage<15, 19, IND,  false, true >(H, xg, ws + O_AND2, WHS, ab2, H, sq, tid, wid, l16, lhi);
  __syncthreads();
  // OR (folded W1)
  stage<10, 29, MIDD, true,  false>(H, xg, ws + O_OR1,  WXS, ob1, H, sq, tid, wid, l16, lhi);
  __syncthreads();
  stage<15, 19, IND,  false, true >(H, xg, ws + O_OR2,  WHS, ob2, H, sq, tid, wid, l16, lhi);

#pragma unroll
  for (int off = 32; off > 0; off >>= 1) sq += __shfl_down(sq, off);
  if (lane == 0) wsum[wid] = sq;
  __syncthreads();
  if (tid == 0) {
    float s = 0.f;
#pragma unroll
    for (int w = 0; w < 8; w++) s += wsum[w];
    atomicAdd(out, s);
  }
}

__global__ void finalize(float* out) {
  out[0] *= (1.0f / (3.0f * (float)BATCH * (float)IND));
}

extern "C" void kernel_launch(void* const* d_in, const int* in_sizes, int n_in,
                              void* d_out, int out_size, void* d_ws, size_t ws_size,
                              hipStream_t stream) {
  const float* x   = (const float*)d_in[0];
  const float* nw1 = (const float*)d_in[1];
  const float* nb1 = (const float*)d_in[2];
  const float* nw2 = (const float*)d_in[3];
  const float* nb2 = (const float*)d_in[4];
  const float* aw1 = (const float*)d_in[5];
  const float* ab1 = (const float*)d_in[6];
  const float* aw2 = (const float*)d_in[7];
  const float* ab2 = (const float*)d_in[8];
  const float* ow1 = (const float*)d_in[9];
  const float* ob1 = (const float*)d_in[10];
  const float* ow2 = (const float*)d_in[11];
  const float* ob2 = (const float*)d_in[12];
  unsigned short* ws = (unsigned short*)d_ws;
  float* out = (float*)d_out;

  hipMemsetAsync(d_out, 0, sizeof(float), stream);

  int prep_blocks = (WS_ELEMS + 255) / 256;
  prep_weights<<<prep_blocks, 256, 0, stream>>>(nw1, nw2, aw1, aw2, ow1, ow2, ws);

  hipFuncSetAttribute((const void*)fused,
                      hipFuncAttributeMaxDynamicSharedMemorySize, LDS_BYTES);
  fused<<<NBLK, NTHR, LDS_BYTES, stream>>>(x, ws, nb1, nb2, ab1, ab2, ob1, ob2, out);

  finalize<<<1, 1, 0, stream>>>(out);
}

// Round 16
// 821.524 us; speedup vs baseline: 1.2876x; 1.2876x over previous
//
#include <hip/hip_runtime.h>

typedef __attribute__((ext_vector_type(8))) short short8;
typedef __attribute__((ext_vector_type(8))) __bf16 bf16x8;
typedef __attribute__((ext_vector_type(4))) float f32x4;

#define BATCH   131072
#define IND     300
#define MIDD    450
#define XS      328   // X LDS row stride (elems); 656B
#define HS      488   // H LDS row stride (elems); 976B
#define WXS     320   // W global row stride, K300-class: 640B = 64B-aligned rows
#define WHS     480   // W global row stride, K450-class: 960B = 64B-aligned rows
#define BM      48    // X+H = 78336B LDS -> 2 blocks/CU if total regs <= 128
#define NTHR    512
#define NBLK    ((BATCH + BM - 1) / BM)   // 2731 (last block: 32 valid rows)

constexpr int SZ1 = 464 * WXS;    // [464][320] padded N450,K320 weights (row-major, bf16)
constexpr int SZ2 = 304 * WHS;    // [304][480] padded N300,K480 weights
constexpr int O_NOT1 = 0;
constexpr int O_NOT2 = SZ1;
constexpr int O_AND1 = SZ1 + SZ2;
constexpr int O_AND2 = 2 * SZ1 + SZ2;
constexpr int O_OR1  = 2 * SZ1 + 2 * SZ2;
constexpr int O_OR2  = 3 * SZ1 + 2 * SZ2;
constexpr int WS_ELEMS = 3 * SZ1 + 3 * SZ2;

constexpr int XBYTES = BM * XS * 2;           // 31488
constexpr int HBYTES = BM * HS * 2;           // 46848
constexpr int LDS_BYTES = XBYTES + HBYTES;    // 78336

__device__ __forceinline__ unsigned short f2b(float f) {
  unsigned u = __builtin_bit_cast(unsigned, f);
  u = (u + 0x7FFFu + ((u >> 16) & 1u)) >> 16;   // RNE
  return (unsigned short)u;
}
__device__ __forceinline__ float b2f(unsigned short h) {
  unsigned u = ((unsigned)h) << 16;
  return __builtin_bit_cast(float, u);
}
// Builtin + (512,4): compiler may place acc AND operand buffers in AGPRs
// (ISA sec.10: A,B,C/D all readable from AGPR) -> total unified <=128 ->
// 4 waves/SIMD. Inline-asm "v" (R5/R7) forced acc->arch VGPR under the cap
// -> scratch spill; builtin without cap (R13) sprawled to 128 arch.
__device__ __forceinline__ f32x4 mfma16(short8 a, short8 b, f32x4 c) {
  return __builtin_amdgcn_mfma_f32_16x16x32_bf16(
      __builtin_bit_cast(bf16x8, a), __builtin_bit_cast(bf16x8, b), c, 0, 0, 0);
}

// ---- weight prep: f32 -> bf16, zero-padded, 64B-aligned rows; AND/OR W1 folded ----
__global__ void prep_weights(const float* __restrict__ nw1, const float* __restrict__ nw2,
                             const float* __restrict__ aw1, const float* __restrict__ aw2,
                             const float* __restrict__ ow1, const float* __restrict__ ow2,
                             unsigned short* __restrict__ ws)
{
  int idx = blockIdx.x * 256 + threadIdx.x;
  if (idx < 3 * SZ1) {
    int r = idx / SZ1, off = idx % SZ1;
    int n = off / WXS, k = off % WXS;
    float v = 0.f;
    if (n < MIDD && k < IND) {
      if (r == 0) v = nw1[n * IND + k];
      else {
        const float* s = (r == 1) ? aw1 : ow1;
        v = s[n * 2 * IND + k] + s[n * 2 * IND + IND + k];   // fold concat([x,x])
      }
    }
    int base = (r == 0) ? O_NOT1 : (r == 1) ? O_AND1 : O_OR1;
    ws[base + off] = f2b(v);
  } else if (idx < WS_ELEMS) {
    int i2 = idx - 3 * SZ1;
    int r = i2 / SZ2, off = i2 % SZ2;
    int n = off / WHS, k = off % WHS;
    float v = 0.f;
    if (n < IND && k < MIDD) {
      const float* s = (r == 0) ? nw2 : (r == 1) ? aw2 : ow2;
      v = s[n * MIDD + k];
    }
    int base = (r == 0) ? O_NOT2 : (r == 1) ? O_AND2 : O_OR2;
    ws[base + off] = f2b(v);
  }
}

// ---- one GEMM stage: OUT[48][N] = leaky(IN[48][K] @ W^T + b); MSE variant fuses vs X ----
// A from LDS (2-buf depth-1), B from L2 (2-buf depth-1). TLP (4 waves/SIMD) hides
// latency instead of deep ILP pipelines (m97 philosophy).
// Frags (16x16x32 bf16): A lane m=l&15,k=8*(l>>4)+i ; B lane n=l&15,k same
// D lane: n=l&15, m=(l>>4)*4+r  (validated rounds 1-15)
template <int KB, int NT, int N, bool MSE>
__device__ __forceinline__ void stage(const unsigned short* __restrict__ IN, int in_stride,
                                      const unsigned short* __restrict__ Wg, int wg_stride,
                                      const float* __restrict__ bias,
                                      unsigned short* __restrict__ Hout,
                                      const unsigned short* __restrict__ XT,
                                      float& sq, int rows, int tid, int wn, int l16, int lhi)
{
  constexpr int NJ = (NT + 7) / 8;
  f32x4 acc[3][NJ];
#pragma unroll
  for (int m = 0; m < 3; m++)
#pragma unroll
    for (int j = 0; j < NJ; j++) acc[m][j] = f32x4{0.f, 0.f, 0.f, 0.f};

  const unsigned short* ap[3];
#pragma unroll
  for (int m = 0; m < 3; m++) ap[m] = IN + (m * 16 + l16) * in_stride + lhi * 8;
  const unsigned short* bp[NJ];
#pragma unroll
  for (int j = 0; j < NJ; j++) {
    int nt = wn + 8 * j;
    int row = (nt < NT ? nt : 0) * 16 + l16;      // clamp invalid tiles to row 0
    bp[j] = Wg + row * wg_stride + lhi * 8;
  }

  short8 a0[3], a1[3], b0[NJ], b1[NJ];

#define LA_(buf, kk)                                                     \
  { _Pragma("unroll") for (int m = 0; m < 3; m++)                        \
      buf[m] = *(const short8*)(ap[m] + (kk) * 32); }
#define LB_(buf, kk)                                                     \
  { _Pragma("unroll") for (int j = 0; j < NJ; j++)                       \
      if (wn + 8 * j < NT) buf[j] = *(const short8*)(bp[j] + (kk) * 32); }

  LB_(b0, 0);
  LA_(a0, 0);

#pragma unroll
  for (int kb = 0; kb < KB; kb++) {
    short8* ac = (kb & 1) ? a1 : a0;
    short8* an = (kb & 1) ? a0 : a1;
    short8* bc = (kb & 1) ? b1 : b0;
    short8* bn = (kb & 1) ? b0 : b1;
    if (kb + 1 < KB) LB_(bn, kb + 1);     // depth-1 B prefetch
    if (kb + 1 < KB) LA_(an, kb + 1);     // depth-1 A prefetch
#pragma unroll
    for (int j = 0; j < NJ; j++) {
      if (wn + 8 * j < NT) {
#pragma unroll
        for (int m = 0; m < 3; m++) acc[m][j] = mfma16(ac[m], bc[j], acc[m][j]);
      }
    }
  }
#undef LA_
#undef LB_

  if (!MSE) __syncthreads();   // in-place H overwrite: all waves done reading IN

#pragma unroll
  for (int j = 0; j < NJ; j++) {
    int nt = wn + 8 * j;
    if (nt >= NT) continue;
    int col = nt * 16 + l16;
    bool valid = col < N;
    float bv = valid ? bias[col] : 0.f;
#pragma unroll
    for (int m = 0; m < 3; m++) {
#pragma unroll
      for (int r = 0; r < 4; r++) {
        int row = m * 16 + lhi * 4 + r;
        float v = acc[m][j][r] + bv;
        v = v > 0.f ? v : 0.1f * v;
        if (MSE) {
          if (valid && row < rows) { float d = b2f(XT[row * XS + col]) - v; sq += d * d; }
        } else {
          if (valid) Hout[row * HS + col] = f2b(v);
        }
      }
    }
  }
  if (!MSE && N == IND) {
    // zero pad cols [300,320) so the next K=320 read sees zeros
    for (int i = tid; i < BM * 20; i += NTHR) {
      int r = i / 20, c = i - r * 20;
      Hout[r * HS + IND + c] = 0;
    }
  }
}

__global__ __launch_bounds__(NTHR, 4)
void fused(const float* __restrict__ x, const unsigned short* __restrict__ ws,
           const float* __restrict__ nb1, const float* __restrict__ nb2,
           const float* __restrict__ ab1, const float* __restrict__ ab2,
           const float* __restrict__ ob1, const float* __restrict__ ob2,
           float* __restrict__ out)
{
  extern __shared__ __align__(16) char smem[];
  unsigned short* X = (unsigned short*)smem;                 // [48][XS]
  unsigned short* H = (unsigned short*)(smem + XBYTES);      // [48][HS]
  __shared__ float wsum[8];
  int tid = threadIdx.x, wid = tid >> 6, lane = tid & 63;
  int l16 = lane & 15, lhi = lane >> 4;

  // zero X+H (K-pad columns and tail rows must be 0)
  for (int i = tid; i < LDS_BYTES / 4; i += NTHR) ((unsigned*)smem)[i] = 0u;
  __syncthreads();

  int row0 = blockIdx.x * BM;
  int rows = (row0 + BM <= BATCH) ? BM : (BATCH - row0);
  for (int i = tid; i < rows * IND; i += NTHR) {
    int r = i / IND, c = i - r * IND;
    X[r * XS + c] = f2b(x[(size_t)(row0 + r) * IND + c]);
  }
  __syncthreads();

  float sq = 0.f;
  // NOT(NOT(x))
  stage<10, 29, MIDD, false>(X, XS, ws + O_NOT1, WXS, nb1, H, X, sq, rows, tid, wid, l16, lhi);
  __syncthreads();
  stage<15, 19, IND,  false>(H, HS, ws + O_NOT2, WHS, nb2, H, X, sq, rows, tid, wid, l16, lhi);
  __syncthreads();
  stage<10, 29, MIDD, false>(H, HS, ws + O_NOT1, WXS, nb1, H, X, sq, rows, tid, wid, l16, lhi);
  __syncthreads();
  stage<15, 19, IND,  true >(H, HS, ws + O_NOT2, WHS, nb2, H, X, sq, rows, tid, wid, l16, lhi);
  __syncthreads();
  // AND (folded W1)
  stage<10, 29, MIDD, false>(X, XS, ws + O_AND1, WXS, ab1, H, X, sq, rows, tid, wid, l16, lhi);
  __syncthreads();
  stage<15, 19, IND,  true >(H, HS, ws + O_AND2, WHS, ab2, H, X, sq, rows, tid, wid, l16, lhi);
  __syncthreads();
  // OR (folded W1)
  stage<10, 29, MIDD, false>(X, XS, ws + O_OR1,  WXS, ob1, H, X, sq, rows, tid, wid, l16, lhi);
  __syncthreads();
  stage<15, 19, IND,  true >(H, HS, ws + O_OR2,  WHS, ob2, H, X, sq, rows, tid, wid, l16, lhi);

#pragma unroll
  for (int off = 32; off > 0; off >>= 1) sq += __shfl_down(sq, off);
  if (lane == 0) wsum[wid] = sq;
  __syncthreads();
  if (tid == 0) {
    float s = 0.f;
#pragma unroll
    for (int w = 0; w < 8; w++) s += wsum[w];
    atomicAdd(out, s);
  }
}

__global__ void finalize(float* out) {
  out[0] *= (1.0f / (3.0f * (float)BATCH * (float)IND));
}

extern "C" void kernel_launch(void* const* d_in, const int* in_sizes, int n_in,
                              void* d_out, int out_size, void* d_ws, size_t ws_size,
                              hipStream_t stream) {
  const float* x   = (const float*)d_in[0];
  const float* nw1 = (const float*)d_in[1];
  const float* nb1 = (const float*)d_in[2];
  const float* nw2 = (const float*)d_in[3];
  const float* nb2 = (const float*)d_in[4];
  const float* aw1 = (const float*)d_in[5];
  const float* ab1 = (const float*)d_in[6];
  const float* aw2 = (const float*)d_in[7];
  const float* ab2 = (const float*)d_in[8];
  const float* ow1 = (const float*)d_in[9];
  const float* ob1 = (const float*)d_in[10];
  const float* ow2 = (const float*)d_in[11];
  const float* ob2 = (const float*)d_in[12];
  unsigned short* ws = (unsigned short*)d_ws;
  float* out = (float*)d_out;

  hipMemsetAsync(d_out, 0, sizeof(float), stream);

  int prep_blocks = (WS_ELEMS + 255) / 256;
  prep_weights<<<prep_blocks, 256, 0, stream>>>(nw1, nw2, aw1, aw2, ow1, ow2, ws);

  hipFuncSetAttribute((const void*)fused,
                      hipFuncAttributeMaxDynamicSharedMemorySize, LDS_BYTES);
  fused<<<NBLK, NTHR, LDS_BYTES, stream>>>(x, ws, nb1, nb2, ab1, ab2, ob1, ob2, out);

  finalize<<<1, 1, 0, stream>>>(out);
}